// Round 12
// baseline (142.648 us; speedup 1.0000x reference)
//
#include <hip/hip_runtime.h>

// CGCConv: out = (scatter_add(ew*pr[src]*x[src], dst) + x) @ W.T + b
// N=50000, E=800000, D=96, fp32.
//
// Round 12 = Round 11 (141.5us best) + zero-padded aligned node runs:
//  - k_sortB pads each node's entry run to a multiple of 4 with zero entries
//    (src=0, coef=+0 -> exact zero contribution); offsets from padded scan.
//    Output u32 region has 2x slots, so padding always fits.
//  - k_pull: aligned uint4 entry loads (1 vec load / 4 edges), NO scalar
//    tail, unroll to 16 outstanding gathers for MLP.
//  - prep / MFMA gemm unchanged from R11.
// Pipeline (5 launches): zero -> prep -> sortB -> pull -> gemm.

constexpr int NN = 50000;
constexpr int NE = 800000;
constexpr int DD = 96;
constexpr int NB = 196;                       // buckets: dst>>8 (256 nodes)
constexpr int CAPB = 4608;                    // mu=4082 + 8 sigma
constexpr int EPB = 4096;                     // edges per binA block
constexpr int NBLK = (NE + EPB - 1) / EPB;    // 196
constexpr int NCVT = (NN * DD / 4 + 511) / 512;  // 2344 cvt blocks

using s8v = __attribute__((ext_vector_type(8))) short;   // 8 bf16
using f4v = __attribute__((ext_vector_type(4))) float;   // 4 fp32

__device__ inline unsigned short f2bf(float f) {    // RNE fp32->bf16
    unsigned u = __float_as_uint(f);
    return (unsigned short)((u + 0x7FFFu + ((u >> 16) & 1u)) >> 16);
}
__device__ inline float bfh(unsigned short v) {
    return __uint_as_float((unsigned)v << 16);
}
__device__ inline unsigned long long pack_e(int meta, float c) {
    return (unsigned long long)(unsigned)meta |
           ((unsigned long long)(unsigned)__float_as_uint(c) << 32);
}

__global__ __launch_bounds__(256) void k_zero(int* __restrict__ cur1) {
    if (threadIdx.x < NB) cur1[threadIdx.x] = 0;
}

// Blocks [0,NBLK): bin 4096 edges -> LDS counting-sort by bucket -> coalesced
// run writes. Entry u64 = {src:16 | dloc:8 | bucket:8 | coef_f32:32}.
// Blocks [NBLK,..): y16 = bf16(x).
__global__ __launch_bounds__(512) void k_prep(const int* __restrict__ src,
                                              const int* __restrict__ dst,
                                              const float* __restrict__ ew,
                                              const float* __restrict__ pr,
                                              int* __restrict__ cur1,
                                              unsigned long long* __restrict__ stage,
                                              const float4* __restrict__ x4,
                                              ushort4* __restrict__ y16v) {
    int tid = threadIdx.x;
    if (blockIdx.x >= NBLK) {                 // cvt phase
        int i = (blockIdx.x - NBLK) * 512 + tid;
        if (i < NN * DD / 4) {
            float4 v = x4[i];
            y16v[i] = make_ushort4(f2bf(v.x), f2bf(v.y), f2bf(v.z), f2bf(v.w));
        }
        return;
    }
    __shared__ int h[256];
    __shared__ int gb[256];
    __shared__ int sc[256];
    __shared__ unsigned long long sorted[EPB];   // 32 KB
    for (int i = tid; i < 256; i += 512) h[i] = 0;
    __syncthreads();
    int base = blockIdx.x * EPB;
    int n = min(EPB, NE - base);

    unsigned long long ent[8]; int bkt[8]; int lrk[8];
    #pragma unroll
    for (int j = 0; j < 8; j++) {
        int e = base + j * 512 + tid;
        bkt[j] = -1;
        if (e < NE) {
            int d = dst[e];
            int s = src[e];
            float c = ew[e] * pr[s];
            int bk = d >> 8;
            bkt[j] = bk;
            lrk[j] = atomicAdd(&h[bk], 1);
            ent[j] = pack_e(s | ((d & 255) << 16) | (bk << 24), c);
        }
    }
    __syncthreads();
    if (tid < 256) sc[tid] = h[tid];
    __syncthreads();
    #pragma unroll
    for (int o = 1; o < 256; o <<= 1) {
        int t = 0;
        if (tid < 256 && tid >= o) t = sc[tid - o];
        __syncthreads();
        if (tid < 256) sc[tid] += t;             // inclusive scan
        __syncthreads();
    }
    for (int i = tid; i < NB; i += 512)
        gb[i] = h[i] ? atomicAdd(&cur1[i], h[i]) : 0;
    __syncthreads();
    #pragma unroll
    for (int j = 0; j < 8; j++)
        if (bkt[j] >= 0)
            sorted[sc[bkt[j]] - h[bkt[j]] + lrk[j]] = ent[j];
    __syncthreads();
    for (int i = tid; i < n; i += 512) {         // coalesced run writes
        unsigned long long e = sorted[i];
        int bk = ((int)(e >> 24)) & 0xff;
        stage[(size_t)bk * CAPB + gb[bk] + (i - (sc[bk] - h[bk]))] = e;
    }
}

// Per-bucket counting sort by dloc. Output runs padded to 4-entry multiples
// with zero entries (exact zero contribution); u32 {src | coef_bf16<<16}
// written into first half of own region (2*CAPB u32 slots => padding fits).
__global__ __launch_bounds__(512) void k_sortB(unsigned long long* __restrict__ stage,
                                               const int* __restrict__ cur1,
                                               int* __restrict__ offs,
                                               int* __restrict__ counts) {
    __shared__ int h[256];
    __shared__ int pc[256];                      // padded counts -> incl scan
    __shared__ unsigned sorted[CAPB + 768];      // padded total <= n + 256*3
    int b = blockIdx.x;
    int tid = threadIdx.x;
    size_t base = (size_t)b * CAPB;
    int n = cur1[b];

    for (int i = tid; i < 256; i += 512) h[i] = 0;
    __syncthreads();

    unsigned e32[9]; int dl[9]; int lrk[9];
    int m = 0;
    for (int i = tid; i < n; i += 512) {
        unsigned long long e = stage[base + i];
        int dloc = ((int)(e >> 16)) & 0xff;
        unsigned cb = (unsigned)(e >> 32);       // coef fp32 bits
        unsigned cbf = (cb + 0x7FFFu + ((cb >> 16) & 1u)) >> 16;  // bf16
        e32[m] = ((unsigned)e & 0xffffu) | (cbf << 16);
        dl[m] = dloc;
        lrk[m] = atomicAdd(&h[dloc], 1);
        m++;
    }
    __syncthreads();
    if (tid < 256) pc[tid] = (h[tid] + 3) & ~3;
    __syncthreads();
    #pragma unroll
    for (int o = 1; o < 256; o <<= 1) {
        int t = 0;
        if (tid < 256 && tid >= o) t = pc[tid - o];
        __syncthreads();
        if (tid < 256) pc[tid] += t;             // inclusive (padded)
        __syncthreads();
    }
    int ptot = pc[255];
    for (int i = tid; i < ptot; i += 512) sorted[i] = 0;   // zero pads
    __syncthreads();
    m = 0;
    for (int i = tid; i < n; i += 512) {
        int d = dl[m];
        int pbeg = pc[d] - ((h[d] + 3) & ~3);    // padded exclusive
        sorted[pbeg + lrk[m]] = e32[m];
        m++;
    }
    __syncthreads();
    unsigned* outp = (unsigned*)(stage + base);  // first half of own region
    for (int i = tid; i < ptot; i += 512) outp[i] = sorted[i];
    if (tid < 256) {
        int d = (b << 8) + tid;
        if (d < NN) {
            offs[d] = (int)(2 * base) + pc[tid] - ((h[tid] + 3) & ~3);
            counts[d] = h[tid];
        }
    }
}

// Pull-aggregate: 8 nodes/block, 32 lanes/node, lanes 0..23 own one ushort4.
// Entry runs are 16B-aligned, zero-padded to x4 => pure uint4 loads, no tail.
// Unroll 16 for MLP. Writes io16 = bf16(aggr + x).
__global__ __launch_bounds__(256) void k_pull(const ushort4* __restrict__ y16v,
                                              const float4* __restrict__ x4,
                                              const int* __restrict__ offs,
                                              const int* __restrict__ counts,
                                              const unsigned* __restrict__ ep,
                                              ushort4* __restrict__ io16v) {
    int g = blockIdx.x * 8 + (threadIdx.x >> 5);
    int lane = threadIdx.x & 31;
    if (g >= NN || lane >= 24) return;
    int beg = offs[g];                           // multiple of 4 (16B-aligned)
    int degp = (counts[g] + 3) & ~3;             // padded degree
    const uint4* ep4 = (const uint4*)(ep + beg);
    float ax = 0.f, ay = 0.f, az = 0.f, aw = 0.f;
    int k = 0;
    for (; k + 16 <= degp; k += 16) {
        uint4 E0 = ep4[(k >> 2)], E1 = ep4[(k >> 2) + 1];
        uint4 E2 = ep4[(k >> 2) + 2], E3 = ep4[(k >> 2) + 3];
        unsigned e[16] = {E0.x, E0.y, E0.z, E0.w, E1.x, E1.y, E1.z, E1.w,
                          E2.x, E2.y, E2.z, E2.w, E3.x, E3.y, E3.z, E3.w};
        ushort4 u[16];
        #pragma unroll
        for (int j = 0; j < 16; j++)
            u[j] = y16v[(size_t)(e[j] & 0xffff) * 24 + lane];
        #pragma unroll
        for (int j = 0; j < 16; j++) {
            float c = bfh((unsigned short)(e[j] >> 16));
            ax += c * bfh(u[j].x);
            ay += c * bfh(u[j].y);
            az += c * bfh(u[j].z);
            aw += c * bfh(u[j].w);
        }
    }
    for (; k + 8 <= degp; k += 8) {
        uint4 E0 = ep4[(k >> 2)], E1 = ep4[(k >> 2) + 1];
        unsigned e[8] = {E0.x, E0.y, E0.z, E0.w, E1.x, E1.y, E1.z, E1.w};
        ushort4 u[8];
        #pragma unroll
        for (int j = 0; j < 8; j++)
            u[j] = y16v[(size_t)(e[j] & 0xffff) * 24 + lane];
        #pragma unroll
        for (int j = 0; j < 8; j++) {
            float c = bfh((unsigned short)(e[j] >> 16));
            ax += c * bfh(u[j].x);
            ay += c * bfh(u[j].y);
            az += c * bfh(u[j].z);
            aw += c * bfh(u[j].w);
        }
    }
    for (; k < degp; k += 4) {
        uint4 E0 = ep4[(k >> 2)];
        unsigned e[4] = {E0.x, E0.y, E0.z, E0.w};
        ushort4 u[4];
        #pragma unroll
        for (int j = 0; j < 4; j++)
            u[j] = y16v[(size_t)(e[j] & 0xffff) * 24 + lane];
        #pragma unroll
        for (int j = 0; j < 4; j++) {
            float c = bfh((unsigned short)(e[j] >> 16));
            ax += c * bfh(u[j].x);
            ay += c * bfh(u[j].y);
            az += c * bfh(u[j].z);
            aw += c * bfh(u[j].w);
        }
    }
    float4 xn = x4[(size_t)g * 24 + lane];
    io16v[(size_t)g * 24 + lane] = make_ushort4(f2bf(ax + xn.x), f2bf(ay + xn.y),
                                                f2bf(az + xn.z), f2bf(aw + xn.w));
}

// MFMA GEMM (unchanged from R11, layouts verified by absmax):
// out[r,o] = sum_d io16[r,d]*W[o,d] + b[o], fp32 out.
__global__ __launch_bounds__(256) void k_gemm(const unsigned short* __restrict__ io16,
                                              const float* __restrict__ W,
                                              const float* __restrict__ b,
                                              float* __restrict__ out) {
    __shared__ short bfr[18 * 64 * 8];     // 18 frags x 64 lanes x 8 bf16 = 18.4KB
    int tid = threadIdx.x;
    for (int i = tid; i < 18 * 512; i += 256) {
        int f = i >> 9, r = i & 511;
        int lane = r >> 3, j = r & 7;
        int ks = f / 6, nt = f - 6 * ks;
        int n = nt * 16 + (lane & 15);
        int k = ks * 32 + (lane >> 4) * 8 + j;
        bfr[i] = (short)f2bf(W[n * DD + k]);
    }
    __syncthreads();

    int wave = tid >> 6, lane = tid & 63;
    int quad = lane >> 4, m16 = lane & 15;
    int r0 = blockIdx.x * 64 + wave * 16;
    int rowa = r0 + m16;
    if (rowa >= NN) rowa = NN - 1;           // clamped A read, store masked

    f4v acc[6];
    #pragma unroll
    for (int nt = 0; nt < 6; nt++) acc[nt] = (f4v){0.f, 0.f, 0.f, 0.f};

    #pragma unroll
    for (int ks = 0; ks < 3; ks++) {
        s8v a = *(const s8v*)(io16 + (size_t)rowa * DD + ks * 32 + quad * 8);
        #pragma unroll
        for (int nt = 0; nt < 6; nt++) {
            s8v bb = *(const s8v*)&bfr[((ks * 6 + nt) * 64 + lane) * 8];
            acc[nt] = __builtin_amdgcn_mfma_f32_16x16x32_bf16(a, bb, acc[nt], 0, 0, 0);
        }
    }

    #pragma unroll
    for (int nt = 0; nt < 6; nt++) {
        float bias = b[nt * 16 + m16];
        #pragma unroll
        for (int reg = 0; reg < 4; reg++) {
            int rr = r0 + quad * 4 + reg;
            if (rr < NN)
                out[(size_t)rr * DD + nt * 16 + m16] = acc[nt][reg] + bias;
        }
    }
}

extern "C" void kernel_launch(void* const* d_in, const int* in_sizes, int n_in,
                              void* d_out, int out_size, void* d_ws, size_t ws_size,
                              hipStream_t stream) {
    const float* x  = (const float*)d_in[0];
    const int*   ei = (const int*)d_in[1];   // [2,E]: [0..E)=src, [E..2E)=dst
    const float* ew = (const float*)d_in[2];
    const float* pr = (const float*)d_in[3];
    const float* W  = (const float*)d_in[4];
    const float* b  = (const float*)d_in[5];
    float* out = (float*)d_out;

    // ws layout (~26.8 MB)
    unsigned long long* stage = (unsigned long long*)d_ws;       // NB*CAPB u64
    unsigned short* y16 = (unsigned short*)(stage + (size_t)NB * CAPB);  // 9.6MB
    int* cur1   = (int*)(y16 + (size_t)NN * DD);      // 196
    int* offs   = cur1 + NB;                          // 50000
    int* counts = offs + NN;                          // 50000
    unsigned short* io16 = (unsigned short*)(counts + NN);       // 9.6MB

    const int* src = ei;
    const int* dst = ei + NE;

    k_zero<<<1, 256, 0, stream>>>(cur1);
    k_prep<<<NBLK + NCVT, 512, 0, stream>>>(src, dst, ew, pr, cur1, stage,
                                            (const float4*)x, (ushort4*)y16);
    k_sortB<<<NB, 512, 0, stream>>>(stage, cur1, offs, counts);
    k_pull<<<(NN + 7) / 8, 256, 0, stream>>>((const ushort4*)y16, (const float4*)x,
                                             offs, counts, (const unsigned*)stage,
                                             (ushort4*)io16);
    k_gemm<<<(NN + 63) / 64, 256, 0, stream>>>(io16, W, b, out);
}